// Round 6
// baseline (189.622 us; speedup 1.0000x reference)
//
#include <hip/hip_runtime.h>

#define NN   4096
#define FIN  512
#define FOUT 64
#define NH   8
#define ALPHA 0.2f

typedef __attribute__((ext_vector_type(8))) short bf16x8;
typedef __attribute__((ext_vector_type(4))) float f32x4;

__device__ __forceinline__ unsigned short f2bf(float x) {
    unsigned u = __float_as_uint(x);
    return (unsigned short)((u + 0x7fffu + ((u >> 16) & 1u)) >> 16);  // RNE
}

__device__ __forceinline__ void gload_lds16(const void* g, void* l) {
    __builtin_amdgcn_global_load_lds(
        (const __attribute__((address_space(1))) unsigned int*)g,
        (__attribute__((address_space(3))) unsigned int*)l, 16, 0, 0);
}

// ---------------------------------------------------------------------------
// K0 (merged):
//   blocks [0, BITBLK):    adj -> 64-bit masks via ballot, grid-stride
//   blocks [BITBLK, +512): Wh GEMM + f1/f2 + bf16 WhTs (tiled+swizzled) epi
// WhTs layout: [h][tile][8192 B]; 16B chunk (o, kbyte) at byte
//   o*128 + (kbyte ^ ((o&7)<<4))  — k3's LDS swizzle order, so k3 stages it
// linearly with global_load_lds (rule #21: pre-swizzled source, linear dest).
// ---------------------------------------------------------------------------
#define BITBLK 2048
#define NWCHUNK (NN * NN / 64)    // 262144 chunks of 64 ints

__global__ __launch_bounds__(256) void k0(const float* __restrict__ x,
                                          const int*   __restrict__ adj,
                                          const float* __restrict__ W,
                                          const float* __restrict__ aw,
                                          unsigned long long* __restrict__ bits,
                                          unsigned short* __restrict__ WhTs,
                                          float* __restrict__ f1,
                                          float* __restrict__ f2) {
    __shared__ float As[16][68];
    __shared__ float Bs[16][68];
    __shared__ unsigned short Tb[64][80];
    __shared__ float r1[64][16];
    __shared__ float r2[64][16];
    const int t = threadIdx.x;

    if (blockIdx.x < BITBLK) {
        const int wv   = blockIdx.x * 4 + (t >> 6);   // 0..8191
        const int lane = t & 63;
        #pragma unroll 4
        for (int it = 0; it < NWCHUNK / (BITBLK * 4); ++it) {
            const int c = wv + it * (BITBLK * 4);
            int v = adj[(size_t)c * 64 + lane];
            unsigned long long m = __ballot(v > 0);
            if (lane == 0) bits[c] = m;
        }
        return;
    }

    const int bx   = blockIdx.x - BITBLK;    // 0..511
    const int h    = bx >> 6;
    const int nti  = bx & 63;
    const int row0 = nti * 64;
    const int tr = t >> 4, tc = t & 15;
    const int ar = t >> 2, ak = t & 3;
    const int bk = t >> 4, bo = t & 15;
    const float* WH = W + (size_t)h * FIN * FOUT;
    float acc[4][4] = {};

    for (int k0i = 0; k0i < FIN; k0i += 16) {
        __syncthreads();
        float4 av = *(const float4*)&x[(size_t)(row0 + ar) * FIN + k0i + ak * 4];
        As[ak*4+0][ar] = av.x; As[ak*4+1][ar] = av.y;
        As[ak*4+2][ar] = av.z; As[ak*4+3][ar] = av.w;
        *(float4*)&Bs[bk][bo*4] =
            *(const float4*)&WH[(size_t)(k0i + bk) * FOUT + bo*4];
        __syncthreads();
        #pragma unroll
        for (int kk = 0; kk < 16; ++kk) {
            float4 a4 = *(const float4*)&As[kk][tr*4];
            float4 b4 = *(const float4*)&Bs[kk][tc*4];
            float a[4] = {a4.x, a4.y, a4.z, a4.w};
            float b[4] = {b4.x, b4.y, b4.z, b4.w};
            #pragma unroll
            for (int i = 0; i < 4; ++i)
                #pragma unroll
                for (int j = 0; j < 4; ++j)
                    acc[i][j] = fmaf(a[i], b[j], acc[i][j]);
        }
    }

    // epilogue: f1/f2 partials + bf16 transpose tile
    float a1v[4], a2v[4];
    #pragma unroll
    for (int j = 0; j < 4; ++j) {
        a1v[j] = aw[h * 2 * FOUT + tc*4 + j];
        a2v[j] = aw[h * 2 * FOUT + FOUT + tc*4 + j];
    }
    #pragma unroll
    for (int i = 0; i < 4; ++i) {
        float s1 = 0.f, s2 = 0.f;
        #pragma unroll
        for (int j = 0; j < 4; ++j) {
            s1 = fmaf(acc[i][j], a1v[j], s1);
            s2 = fmaf(acc[i][j], a2v[j], s2);
            Tb[tc*4 + j][tr*4 + i] = f2bf(acc[i][j]);
        }
        r1[tr*4 + i][tc] = s1;
        r2[tr*4 + i][tc] = s2;
    }
    __syncthreads();
    if (t < 64) {
        float s1 = 0.f, s2 = 0.f;
        #pragma unroll
        for (int k = 0; k < 16; ++k) { s1 += r1[t][k]; s2 += r2[t][k]; }
        f1[h * NN + row0 + t] = s1;
        f2[h * NN + row0 + t] = s2;
    }
    // write tile in k3's swizzled byte order (pre-swizzled global source)
    unsigned char* tileB = (unsigned char*)(WhTs + ((size_t)(h * 64) + nti) * 4096);
    #pragma unroll
    for (int i = 0; i < 2; ++i) {
        int c = t + i * 256;                 // 512 chunks of 16 B
        int o = c >> 3, nch = c & 7;
        *(uint4*)(tileB + o * 128 + ((nch * 16) ^ ((o & 7) << 4))) =
            *(const uint4*)&Tb[o][nch * 8];
    }
}

// ---------------------------------------------------------------------------
// K3: fused masked softmax + PV (bf16 MFMA), j-split. PROVEN 2-barrier loop
// (R4 template): sync -> stage(gload)+computeP -> sync -> MFMA.
// Next tile's msk/f2 register-prefetched during MFMA (no sync change).
// ---------------------------------------------------------------------------
__global__ __launch_bounds__(256, 8) void k3_attn(
        const unsigned long long* __restrict__ bits,
        const unsigned short* __restrict__ WhTs,
        const float* __restrict__ f1, const float* __restrict__ f2,
        float* __restrict__ pnum, float* __restrict__ pden) {
    __shared__ unsigned char psB[8192];
    __shared__ unsigned char wsB[8192];
    __shared__ float dred[64][4];
    const int t    = threadIdx.x;
    const int lane = t & 63, wid = t >> 6;
    const int h    = blockIdx.y;
    const int row0 = blockIdx.x * 64;
    const int js   = blockIdx.z, JS = gridDim.z;
    const int ntile = (NN / 64) / JS;
    const int nt0   = js * ntile;
    const int pr   = t >> 2, psub = t & 3;
    const float f1r = f1[h * NN + row0 + pr];
    const float* f2h = f2 + h * NN;
    const unsigned long long* bitsRow = bits + (size_t)(row0 + pr) * 64;
    const unsigned short* WTS = WhTs + (size_t)h * 64 * 4096;
    const int prswz = (pr & 7) << 4;
    f32x4 acc[4] = {};
    float dsum = 0.f;

    // register prefetch state for tile nti: mask + 16 f2 values
    unsigned  curM;  float4 curF[4];
    auto prefetch = [&](int nti, unsigned& M, float4* F) {
        M = (unsigned)(bitsRow[nti] >> (psub << 4)) & 0xFFFFu;
        const float* f2c = f2h + nti * 64 + psub * 16;
        #pragma unroll
        for (int c = 0; c < 4; ++c) F[c] = *(const float4*)&f2c[c * 4];
    };
    prefetch(nt0, curM, curF);

    const int arw = wid * 16 + (lane & 15);
    const int kb  = (lane >> 4) * 16;
    const int aswz = (arw & 7) << 4;

    for (int it = 0; it < ntile; ++it) {
        const int nti = nt0 + it;
        __syncthreads();                       // prev MFMA done reading tiles
        // ---- stage Wh tile: async gload from pre-swizzled source ----
        {
            const unsigned char* gt = (const unsigned char*)(WTS + (size_t)nti * 4096);
            #pragma unroll
            for (int q = 0; q < 2; ++q) {
                const int seg = wid * 2 + q;
                gload_lds16(gt + seg * 1024 + lane * 16, &wsB[seg * 1024]);
            }
        }
        // ---- compute P from prefetched regs ----
        #pragma unroll
        for (int half = 0; half < 2; ++half) {
            unsigned pk[4];
            #pragma unroll
            for (int c2 = 0; c2 < 2; ++c2) {
                const int c = half * 2 + c2;
                float4 f4 = curF[c];
                float e0 = f1r + f4.x, e1 = f1r + f4.y;
                float e2 = f1r + f4.z, e3 = f1r + f4.w;
                e0 = fmaxf(e0, ALPHA * e0); e1 = fmaxf(e1, ALPHA * e1);
                e2 = fmaxf(e2, ALPHA * e2); e3 = fmaxf(e3, ALPHA * e3);
                float p0 = ((curM >> (c*4+0)) & 1u) ? __expf(e0) : 0.f;
                float p1 = ((curM >> (c*4+1)) & 1u) ? __expf(e1) : 0.f;
                float p2 = ((curM >> (c*4+2)) & 1u) ? __expf(e2) : 0.f;
                float p3 = ((curM >> (c*4+3)) & 1u) ? __expf(e3) : 0.f;
                dsum += (p0 + p1) + (p2 + p3);
                pk[c2*2+0] = (unsigned)f2bf(p0) | ((unsigned)f2bf(p1) << 16);
                pk[c2*2+1] = (unsigned)f2bf(p2) | ((unsigned)f2bf(p3) << 16);
            }
            uint4 w = {pk[0], pk[1], pk[2], pk[3]};
            *(uint4*)&psB[pr * 128 + ((psub*32 + half*16) ^ prswz)] = w;
        }
        // issue next tile's register prefetch (completes under MFMA/sync)
        unsigned nxtM = 0; float4 nxtF[4];
        if (it + 1 < ntile) prefetch(nti + 1, nxtM, nxtF);
        __syncthreads();                       // gload drained + psB visible
        // ---- MFMA ----
        #pragma unroll
        for (int ks = 0; ks < 2; ++ks) {
            bf16x8 af = *(const bf16x8*)&psB[arw * 128 + ((ks*64 + kb) ^ aswz)];
            #pragma unroll
            for (int cf = 0; cf < 4; ++cf) {
                int brw = cf * 16 + (lane & 15);
                bf16x8 bfr = *(const bf16x8*)&wsB[brw * 128 + ((ks*64 + kb) ^ ((brw & 7) << 4))];
                acc[cf] = __builtin_amdgcn_mfma_f32_16x16x32_bf16(af, bfr, acc[cf], 0, 0, 0);
            }
        }
        curM = nxtM;
        #pragma unroll
        for (int c = 0; c < 4; ++c) curF[c] = nxtF[c];
    }

    dred[pr][psub] = dsum;
    __syncthreads();

    float* pn = pnum + (((size_t)js * NH + h) * NN + row0) * 64;
    #pragma unroll
    for (int cf = 0; cf < 4; ++cf) {
        int o = cf * 16 + (lane & 15);
        #pragma unroll
        for (int rg = 0; rg < 4; ++rg) {
            int rl = wid * 16 + (lane >> 4) * 4 + rg;
            pn[(size_t)rl * 64 + o] = acc[cf][rg];
        }
    }
    if (t < 64)
        pden[((size_t)js * NH + h) * NN + row0 + t] =
            dred[t][0] + dred[t][1] + dred[t][2] + dred[t][3];
}

// ---------------------------------------------------------------------------
// K4: reduce over JS slices + normalize.
// ---------------------------------------------------------------------------
__global__ __launch_bounds__(256) void k4_red(const float* __restrict__ pnum,
                                              const float* __restrict__ pden,
                                              float* __restrict__ out, int JS) {
    const int idx = blockIdx.x * 256 + threadIdx.x;   // 0..524287
    const int h   = idx >> 16;
    const int rem = idx & 65535;
    const int n   = rem >> 4;
    const int o4  = (rem & 15) * 4;
    float4 s = {0.f, 0.f, 0.f, 0.f};
    float  d = 0.f;
    for (int js = 0; js < JS; ++js) {
        const float* p = pnum + (((size_t)js * NH + h) * NN + n) * 64 + o4;
        float4 v = *(const float4*)p;
        s.x += v.x; s.y += v.y; s.z += v.z; s.w += v.w;
        d += pden[((size_t)js * NH + h) * NN + n];
    }
    float inv = 1.0f / d;
    float4 r = {s.x * inv, s.y * inv, s.z * inv, s.w * inv};
    *(float4*)&out[(size_t)n * (NH * FOUT) + h * FOUT + o4] = r;
}

extern "C" void kernel_launch(void* const* d_in, const int* in_sizes, int n_in,
                              void* d_out, int out_size, void* d_ws, size_t ws_size,
                              hipStream_t stream) {
    const float* x   = (const float*)d_in[0];
    const int*   adj = (const int*)d_in[1];
    const float* W   = (const float*)d_in[2];
    const float* a   = (const float*)d_in[3];
    float* outp = (float*)d_out;

    // workspace layout
    unsigned short* WhTs = (unsigned short*)d_ws;                   // 4 MB (tiled)
    float* f1 = (float*)(WhTs + (size_t)NH * 64 * NN);              // 128 KB
    float* f2 = f1 + NH * NN;                                       // 128 KB
    unsigned long long* bits = (unsigned long long*)(f2 + NH * NN); // 2 MB
    float* pnum = (float*)(bits + (size_t)NN * 64);
    const size_t baseBytes  = (size_t)(pnum - (float*)d_ws) * 4;
    const size_t sliceBytes = (size_t)NH * NN * 65 * 4;             // num+den per slice
    int JS = 1;
    if (ws_size >= baseBytes + 4 * sliceBytes) JS = 4;
    else if (ws_size >= baseBytes + 2 * sliceBytes) JS = 2;
    float* pden = pnum + (size_t)JS * NH * NN * 64;

    k0     <<<dim3(BITBLK + 512), 256, 0, stream>>>(x, adj, W, a, bits, WhTs, f1, f2);
    k3_attn<<<dim3(NN/64, NH, JS), 256, 0, stream>>>(bits, WhTs, f1, f2, pnum, pden);
    k4_red <<<dim3(NN*NH*FOUT/4/256), 256, 0, stream>>>(pnum, pden, outp, JS);
}

// Round 7
// 140.170 us; speedup vs baseline: 1.3528x; 1.3528x over previous
//
#include <hip/hip_runtime.h>

#define NN   4096
#define FIN  512
#define FOUT 64
#define NH   8
#define ALPHA 0.2f
#define ROWS 128

typedef __attribute__((ext_vector_type(8))) short bf16x8;
typedef __attribute__((ext_vector_type(4))) float f32x4;

__device__ __forceinline__ unsigned short f2bf(float x) {
    unsigned u = __float_as_uint(x);
    return (unsigned short)((u + 0x7fffu + ((u >> 16) & 1u)) >> 16);  // RNE
}

// ---------------------------------------------------------------------------
// K0 (merged):
//   blocks [0, BITBLK):    adj -> 64-bit masks via ballot, grid-stride
//   blocks [BITBLK, +512): Wh GEMM + f1/f2 + bf16 WhTs (tiled+swizzled) epi
// WhTs layout: [h][tile][8192 B]; 16B chunk (o, kbyte) at byte
//   o*128 + (kbyte ^ ((o&7)<<4))  — k3's LDS swizzle order; k3 copies it
// linearly into LDS (regular loads + ds_write — NOT gload_lds: that path
// missed L2 on the 64x re-read pattern, R6 FETCH 226 MB).
// ---------------------------------------------------------------------------
#define BITBLK 2048
#define NWCHUNK (NN * NN / 64)    // 262144 chunks of 64 ints

__global__ __launch_bounds__(256) void k0(const float* __restrict__ x,
                                          const int*   __restrict__ adj,
                                          const float* __restrict__ W,
                                          const float* __restrict__ aw,
                                          unsigned long long* __restrict__ bits,
                                          unsigned short* __restrict__ WhTs,
                                          float* __restrict__ f1,
                                          float* __restrict__ f2) {
    __shared__ float As[16][68];
    __shared__ float Bs[16][68];
    __shared__ unsigned short Tb[64][80];
    __shared__ float r1[64][16];
    __shared__ float r2[64][16];
    const int t = threadIdx.x;

    if (blockIdx.x < BITBLK) {
        const int wv   = blockIdx.x * 4 + (t >> 6);   // 0..8191
        const int lane = t & 63;
        #pragma unroll 4
        for (int it = 0; it < NWCHUNK / (BITBLK * 4); ++it) {
            const int c = wv + it * (BITBLK * 4);
            int v = adj[(size_t)c * 64 + lane];
            unsigned long long m = __ballot(v > 0);
            if (lane == 0) bits[c] = m;
        }
        return;
    }

    const int bx   = blockIdx.x - BITBLK;    // 0..511
    const int h    = bx >> 6;
    const int nti  = bx & 63;
    const int row0 = nti * 64;
    const int tr = t >> 4, tc = t & 15;
    const int ar = t >> 2, ak = t & 3;
    const int bk = t >> 4, bo = t & 15;
    const float* WH = W + (size_t)h * FIN * FOUT;
    float acc[4][4] = {};

    for (int k0i = 0; k0i < FIN; k0i += 16) {
        __syncthreads();
        float4 av = *(const float4*)&x[(size_t)(row0 + ar) * FIN + k0i + ak * 4];
        As[ak*4+0][ar] = av.x; As[ak*4+1][ar] = av.y;
        As[ak*4+2][ar] = av.z; As[ak*4+3][ar] = av.w;
        *(float4*)&Bs[bk][bo*4] =
            *(const float4*)&WH[(size_t)(k0i + bk) * FOUT + bo*4];
        __syncthreads();
        #pragma unroll
        for (int kk = 0; kk < 16; ++kk) {
            float4 a4 = *(const float4*)&As[kk][tr*4];
            float4 b4 = *(const float4*)&Bs[kk][tc*4];
            float a[4] = {a4.x, a4.y, a4.z, a4.w};
            float b[4] = {b4.x, b4.y, b4.z, b4.w};
            #pragma unroll
            for (int i = 0; i < 4; ++i)
                #pragma unroll
                for (int j = 0; j < 4; ++j)
                    acc[i][j] = fmaf(a[i], b[j], acc[i][j]);
        }
    }

    // epilogue: f1/f2 partials + bf16 transpose tile
    float a1v[4], a2v[4];
    #pragma unroll
    for (int j = 0; j < 4; ++j) {
        a1v[j] = aw[h * 2 * FOUT + tc*4 + j];
        a2v[j] = aw[h * 2 * FOUT + FOUT + tc*4 + j];
    }
    #pragma unroll
    for (int i = 0; i < 4; ++i) {
        float s1 = 0.f, s2 = 0.f;
        #pragma unroll
        for (int j = 0; j < 4; ++j) {
            s1 = fmaf(acc[i][j], a1v[j], s1);
            s2 = fmaf(acc[i][j], a2v[j], s2);
            Tb[tc*4 + j][tr*4 + i] = f2bf(acc[i][j]);
        }
        r1[tr*4 + i][tc] = s1;
        r2[tr*4 + i][tc] = s2;
    }
    __syncthreads();
    if (t < 64) {
        float s1 = 0.f, s2 = 0.f;
        #pragma unroll
        for (int k = 0; k < 16; ++k) { s1 += r1[t][k]; s2 += r2[t][k]; }
        f1[h * NN + row0 + t] = s1;
        f2[h * NN + row0 + t] = s2;
    }
    // write tile in k3's swizzled byte order (pre-swizzled global source)
    unsigned char* tileB = (unsigned char*)(WhTs + ((size_t)(h * 64) + nti) * 4096);
    #pragma unroll
    for (int i = 0; i < 2; ++i) {
        int c = t + i * 256;                 // 512 chunks of 16 B
        int o = c >> 3, nch = c & 7;
        *(uint4*)(tileB + o * 128 + ((nch * 16) ^ ((o & 7) << 4))) =
            *(const uint4*)&Tb[o][nch * 8];
    }
}

// ---------------------------------------------------------------------------
// K3: fused masked softmax + PV (bf16 MFMA), j-split. Proven 2-barrier
// template (R4): sync -> stage(ds_write)+computeP -> sync -> MFMA.
// ROWS=128 per block (halves Wh re-read), Wh chunk register-prefetched
// one tile ahead (load issued during prev MFMA phase, written after sync).
// ---------------------------------------------------------------------------
__global__ __launch_bounds__(256, 4) void k3_attn(
        const unsigned long long* __restrict__ bits,
        const unsigned short* __restrict__ WhTs,
        const float* __restrict__ f1, const float* __restrict__ f2,
        float* __restrict__ pnum, float* __restrict__ pden) {
    __shared__ unsigned char psB[ROWS * 128];   // 16 KB
    __shared__ unsigned char wsB[8192];         //  8 KB
    __shared__ float dred[ROWS][2];
    const int t    = threadIdx.x;
    const int lane = t & 63, wid = t >> 6;
    const int h    = blockIdx.y;
    const int row0 = blockIdx.x * ROWS;
    const int js   = blockIdx.z, JS = gridDim.z;
    const int ntile = (NN / 64) / JS;
    const int nt0   = js * ntile;
    const int pr   = t >> 1, psub = t & 1;     // row 0..127, j-half 0..1
    const float f1r = f1[h * NN + row0 + pr];
    const float* f2h = f2 + h * NN;
    const unsigned long long* bitsRow = bits + (size_t)(row0 + pr) * 64;
    const unsigned short* WTS = WhTs + (size_t)h * 64 * 4096;
    const int prswz = (pr & 7) << 4;
    f32x4 acc[2][4] = {};
    float dsum = 0.f;

    uint4 wreg0, wreg1;
    auto loadW = [&](int nti, uint4& w0, uint4& w1) {
        const uint4* gt = (const uint4*)(WTS + (size_t)nti * 4096);
        w0 = gt[t];
        w1 = gt[t + 256];
    };
    loadW(nt0, wreg0, wreg1);

    const int kb = (lane >> 4) * 16;
    for (int it = 0; it < ntile; ++it) {
        const int nti = nt0 + it;
        __syncthreads();                       // prev MFMA done reading tiles
        // ---- stage Wh tile: linear ds_write of prefetched regs ----
        *(uint4*)&wsB[t * 16]        = wreg0;
        *(uint4*)&wsB[t * 16 + 4096] = wreg1;
        // ---- compute P: row pr, 32 j's (psub half) ----
        {
            unsigned msk = (unsigned)(bitsRow[nti] >> (psub << 5));
            const float* f2c = f2h + nti * 64 + psub * 32;
            #pragma unroll
            for (int q = 0; q < 4; ++q) {      // 8 j's per chunk
                unsigned pk[4];
                #pragma unroll
                for (int c2 = 0; c2 < 2; ++c2) {
                    float4 f4 = *(const float4*)&f2c[q * 8 + c2 * 4];
                    float e0 = f1r + f4.x, e1 = f1r + f4.y;
                    float e2 = f1r + f4.z, e3 = f1r + f4.w;
                    e0 = fmaxf(e0, ALPHA * e0); e1 = fmaxf(e1, ALPHA * e1);
                    e2 = fmaxf(e2, ALPHA * e2); e3 = fmaxf(e3, ALPHA * e3);
                    const int b = q * 8 + c2 * 4;
                    float p0 = ((msk >> (b+0)) & 1u) ? __expf(e0) : 0.f;
                    float p1 = ((msk >> (b+1)) & 1u) ? __expf(e1) : 0.f;
                    float p2 = ((msk >> (b+2)) & 1u) ? __expf(e2) : 0.f;
                    float p3 = ((msk >> (b+3)) & 1u) ? __expf(e3) : 0.f;
                    dsum += (p0 + p1) + (p2 + p3);
                    pk[c2*2+0] = (unsigned)f2bf(p0) | ((unsigned)f2bf(p1) << 16);
                    pk[c2*2+1] = (unsigned)f2bf(p2) | ((unsigned)f2bf(p3) << 16);
                }
                uint4 w = {pk[0], pk[1], pk[2], pk[3]};
                *(uint4*)&psB[pr * 128 + ((psub*64 + q*16) ^ prswz)] = w;
            }
        }
        // issue next tile's Wh load (completes under MFMA + barrier)
        if (it + 1 < ntile) loadW(nti + 1, wreg0, wreg1);
        __syncthreads();                       // tiles visible
        // ---- MFMA: 2 row-frags x 4 col-frags x 2 k-steps ----
        #pragma unroll
        for (int fg = 0; fg < 2; ++fg) {
            const int arw  = wid * 32 + fg * 16 + (lane & 15);
            const int aswz = (arw & 7) << 4;
            #pragma unroll
            for (int ks = 0; ks < 2; ++ks) {
                bf16x8 af = *(const bf16x8*)&psB[arw * 128 + ((ks*64 + kb) ^ aswz)];
                #pragma unroll
                for (int cf = 0; cf < 4; ++cf) {
                    int brw = cf * 16 + (lane & 15);
                    bf16x8 bfr = *(const bf16x8*)&wsB[brw * 128 + ((ks*64 + kb) ^ ((brw & 7) << 4))];
                    acc[fg][cf] = __builtin_amdgcn_mfma_f32_16x16x32_bf16(af, bfr, acc[fg][cf], 0, 0, 0);
                }
            }
        }
    }

    dred[pr][psub] = dsum;
    __syncthreads();

    float* pn = pnum + (((size_t)js * NH + h) * NN + row0) * 64;
    #pragma unroll
    for (int fg = 0; fg < 2; ++fg)
        #pragma unroll
        for (int cf = 0; cf < 4; ++cf) {
            int o = cf * 16 + (lane & 15);
            #pragma unroll
            for (int rg = 0; rg < 4; ++rg) {
                int rl = wid * 32 + fg * 16 + (lane >> 4) * 4 + rg;
                pn[(size_t)rl * 64 + o] = acc[fg][cf][rg];
            }
        }
    if (t < ROWS)
        pden[((size_t)js * NH + h) * NN + row0 + t] = dred[t][0] + dred[t][1];
}

// ---------------------------------------------------------------------------
// K4: reduce over JS slices + normalize.
// ---------------------------------------------------------------------------
__global__ __launch_bounds__(256) void k4_red(const float* __restrict__ pnum,
                                              const float* __restrict__ pden,
                                              float* __restrict__ out, int JS) {
    const int idx = blockIdx.x * 256 + threadIdx.x;   // 0..524287
    const int h   = idx >> 16;
    const int rem = idx & 65535;
    const int n   = rem >> 4;
    const int o4  = (rem & 15) * 4;
    float4 s = {0.f, 0.f, 0.f, 0.f};
    float  d = 0.f;
    for (int js = 0; js < JS; ++js) {
        const float* p = pnum + (((size_t)js * NH + h) * NN + n) * 64 + o4;
        float4 v = *(const float4*)p;
        s.x += v.x; s.y += v.y; s.z += v.z; s.w += v.w;
        d += pden[((size_t)js * NH + h) * NN + n];
    }
    float inv = 1.0f / d;
    float4 r = {s.x * inv, s.y * inv, s.z * inv, s.w * inv};
    *(float4*)&out[(size_t)n * (NH * FOUT) + h * FOUT + o4] = r;
}

extern "C" void kernel_launch(void* const* d_in, const int* in_sizes, int n_in,
                              void* d_out, int out_size, void* d_ws, size_t ws_size,
                              hipStream_t stream) {
    const float* x   = (const float*)d_in[0];
    const int*   adj = (const int*)d_in[1];
    const float* W   = (const float*)d_in[2];
    const float* a   = (const float*)d_in[3];
    float* outp = (float*)d_out;

    // workspace layout
    unsigned short* WhTs = (unsigned short*)d_ws;                   // 4 MB (tiled)
    float* f1 = (float*)(WhTs + (size_t)NH * 64 * NN);              // 128 KB
    float* f2 = f1 + NH * NN;                                       // 128 KB
    unsigned long long* bits = (unsigned long long*)(f2 + NH * NN); // 2 MB
    float* pnum = (float*)(bits + (size_t)NN * 64);
    const size_t baseBytes  = (size_t)(pnum - (float*)d_ws) * 4;
    const size_t sliceBytes = (size_t)NH * NN * 65 * 4;             // num+den per slice
    int JS = 1;
    if (ws_size >= baseBytes + 4 * sliceBytes) JS = 4;
    else if (ws_size >= baseBytes + 2 * sliceBytes) JS = 2;
    float* pden = pnum + (size_t)JS * NH * NN * 64;

    k0     <<<dim3(BITBLK + 512), 256, 0, stream>>>(x, adj, W, a, bits, WhTs, f1, f2);
    k3_attn<<<dim3(NN/ROWS, NH, JS), 256, 0, stream>>>(bits, WhTs, f1, f2, pnum, pden);
    k4_red <<<dim3(NN*NH*FOUT/4/256), 256, 0, stream>>>(pnum, pden, outp, JS);
}

// Round 8
// 116.202 us; speedup vs baseline: 1.6318x; 1.2063x over previous
//
#include <hip/hip_runtime.h>

#define NN   4096
#define FIN  512
#define FOUT 64
#define NH   8
#define ALPHA 0.2f
#define ROWS 128

typedef __attribute__((ext_vector_type(8))) short bf16x8;
typedef __attribute__((ext_vector_type(4))) float f32x4;

__device__ __forceinline__ unsigned short f2bf(float x) {
    unsigned u = __float_as_uint(x);
    return (unsigned short)((u + 0x7fffu + ((u >> 16) & 1u)) >> 16);  // RNE
}

// ---------------------------------------------------------------------------
// KB: adj -> 64-bit masks. No LDS (full occupancy), 8 loads in flight per
// wave (manual unroll), ballots stored pairwise by lane 0.
// wave wv owns chunks [wv*32, wv*32+32); 2048 blocks x 4 waves = 8192 waves.
// ---------------------------------------------------------------------------
__global__ __launch_bounds__(256) void kb(const int* __restrict__ adj,
                                          unsigned long long* __restrict__ bits) {
    const int wv   = blockIdx.x * 4 + (threadIdx.x >> 6);
    const int lane = threadIdx.x & 63;
    const int base = wv * 32;
    #pragma unroll
    for (int r = 0; r < 4; ++r) {
        int v0 = adj[(size_t)(base + r*8 + 0) * 64 + lane];
        int v1 = adj[(size_t)(base + r*8 + 1) * 64 + lane];
        int v2 = adj[(size_t)(base + r*8 + 2) * 64 + lane];
        int v3 = adj[(size_t)(base + r*8 + 3) * 64 + lane];
        int v4 = adj[(size_t)(base + r*8 + 4) * 64 + lane];
        int v5 = adj[(size_t)(base + r*8 + 5) * 64 + lane];
        int v6 = adj[(size_t)(base + r*8 + 6) * 64 + lane];
        int v7 = adj[(size_t)(base + r*8 + 7) * 64 + lane];
        unsigned long long m0 = __ballot(v0 > 0);
        unsigned long long m1 = __ballot(v1 > 0);
        unsigned long long m2 = __ballot(v2 > 0);
        unsigned long long m3 = __ballot(v3 > 0);
        unsigned long long m4 = __ballot(v4 > 0);
        unsigned long long m5 = __ballot(v5 > 0);
        unsigned long long m6 = __ballot(v6 > 0);
        unsigned long long m7 = __ballot(v7 > 0);
        if (lane == 0) {
            ulonglong2* dst = (ulonglong2*)&bits[base + r*8];
            dst[0] = {m0, m1};
            dst[1] = {m2, m3};
            dst[2] = {m4, m5};
            dst[3] = {m6, m7};
        }
    }
}

// ---------------------------------------------------------------------------
// KG: Wh GEMM + f1/f2 + bf16 WhTs (tiled+swizzled) epilogue (proven R7 code).
// WhTs layout: [h][tile][8192 B]; 16B chunk (o, kbyte) at byte
//   o*128 + (kbyte ^ ((o&7)<<4))  — k3's LDS swizzle order.
// ---------------------------------------------------------------------------
__global__ __launch_bounds__(256) void kg(const float* __restrict__ x,
                                          const float* __restrict__ W,
                                          const float* __restrict__ aw,
                                          unsigned short* __restrict__ WhTs,
                                          float* __restrict__ f1,
                                          float* __restrict__ f2) {
    __shared__ float As[16][68];
    __shared__ float Bs[16][68];
    __shared__ unsigned short Tb[64][80];
    __shared__ float r1[64][16];
    __shared__ float r2[64][16];
    const int t = threadIdx.x;
    const int bx   = blockIdx.x;             // 0..511
    const int h    = bx >> 6;
    const int nti  = bx & 63;
    const int row0 = nti * 64;
    const int tr = t >> 4, tc = t & 15;
    const int ar = t >> 2, ak = t & 3;
    const int bk = t >> 4, bo = t & 15;
    const float* WH = W + (size_t)h * FIN * FOUT;
    float acc[4][4] = {};

    for (int k0i = 0; k0i < FIN; k0i += 16) {
        __syncthreads();
        float4 av = *(const float4*)&x[(size_t)(row0 + ar) * FIN + k0i + ak * 4];
        As[ak*4+0][ar] = av.x; As[ak*4+1][ar] = av.y;
        As[ak*4+2][ar] = av.z; As[ak*4+3][ar] = av.w;
        *(float4*)&Bs[bk][bo*4] =
            *(const float4*)&WH[(size_t)(k0i + bk) * FOUT + bo*4];
        __syncthreads();
        #pragma unroll
        for (int kk = 0; kk < 16; ++kk) {
            float4 a4 = *(const float4*)&As[kk][tr*4];
            float4 b4 = *(const float4*)&Bs[kk][tc*4];
            float a[4] = {a4.x, a4.y, a4.z, a4.w};
            float b[4] = {b4.x, b4.y, b4.z, b4.w};
            #pragma unroll
            for (int i = 0; i < 4; ++i)
                #pragma unroll
                for (int j = 0; j < 4; ++j)
                    acc[i][j] = fmaf(a[i], b[j], acc[i][j]);
        }
    }

    float a1v[4], a2v[4];
    #pragma unroll
    for (int j = 0; j < 4; ++j) {
        a1v[j] = aw[h * 2 * FOUT + tc*4 + j];
        a2v[j] = aw[h * 2 * FOUT + FOUT + tc*4 + j];
    }
    #pragma unroll
    for (int i = 0; i < 4; ++i) {
        float s1 = 0.f, s2 = 0.f;
        #pragma unroll
        for (int j = 0; j < 4; ++j) {
            s1 = fmaf(acc[i][j], a1v[j], s1);
            s2 = fmaf(acc[i][j], a2v[j], s2);
            Tb[tc*4 + j][tr*4 + i] = f2bf(acc[i][j]);
        }
        r1[tr*4 + i][tc] = s1;
        r2[tr*4 + i][tc] = s2;
    }
    __syncthreads();
    if (t < 64) {
        float s1 = 0.f, s2 = 0.f;
        #pragma unroll
        for (int k = 0; k < 16; ++k) { s1 += r1[t][k]; s2 += r2[t][k]; }
        f1[h * NN + row0 + t] = s1;
        f2[h * NN + row0 + t] = s2;
    }
    unsigned char* tileB = (unsigned char*)(WhTs + ((size_t)(h * 64) + nti) * 4096);
    #pragma unroll
    for (int i = 0; i < 2; ++i) {
        int c = t + i * 256;
        int o = c >> 3, nch = c & 7;
        *(uint4*)(tileB + o * 128 + ((nch * 16) ^ ((o & 7) << 4))) =
            *(const uint4*)&Tb[o][nch * 8];
    }
}

// ---------------------------------------------------------------------------
// K3: fused masked softmax + PV (bf16 MFMA), j-split. Proven 2-barrier
// template: sync -> stage(ds_write)+computeP -> sync -> MFMA. ROWS=128,
// Wh chunk register-prefetched one tile ahead.
// ---------------------------------------------------------------------------
__global__ __launch_bounds__(256, 4) void k3_attn(
        const unsigned long long* __restrict__ bits,
        const unsigned short* __restrict__ WhTs,
        const float* __restrict__ f1, const float* __restrict__ f2,
        float* __restrict__ pnum, float* __restrict__ pden) {
    __shared__ unsigned char psB[ROWS * 128];   // 16 KB
    __shared__ unsigned char wsB[8192];         //  8 KB
    __shared__ float dred[ROWS][2];
    const int t    = threadIdx.x;
    const int lane = t & 63, wid = t >> 6;
    const int h    = blockIdx.y;
    const int row0 = blockIdx.x * ROWS;
    const int js   = blockIdx.z, JS = gridDim.z;
    const int ntile = (NN / 64) / JS;
    const int nt0   = js * ntile;
    const int pr   = t >> 1, psub = t & 1;     // row 0..127, j-half 0..1
    const float f1r = f1[h * NN + row0 + pr];
    const float* f2h = f2 + h * NN;
    const unsigned long long* bitsRow = bits + (size_t)(row0 + pr) * 64;
    const unsigned short* WTS = WhTs + (size_t)h * 64 * 4096;
    const int prswz = (pr & 7) << 4;
    f32x4 acc[2][4] = {};
    float dsum = 0.f;

    uint4 wreg0, wreg1;
    auto loadW = [&](int nti, uint4& w0, uint4& w1) {
        const uint4* gt = (const uint4*)(WTS + (size_t)nti * 4096);
        w0 = gt[t];
        w1 = gt[t + 256];
    };
    loadW(nt0, wreg0, wreg1);

    const int kb2 = (lane >> 4) * 16;
    for (int it = 0; it < ntile; ++it) {
        const int nti = nt0 + it;
        __syncthreads();                       // prev MFMA done reading tiles
        *(uint4*)&wsB[t * 16]        = wreg0;
        *(uint4*)&wsB[t * 16 + 4096] = wreg1;
        {
            unsigned msk = (unsigned)(bitsRow[nti] >> (psub << 5));
            const float* f2c = f2h + nti * 64 + psub * 32;
            #pragma unroll
            for (int q = 0; q < 4; ++q) {
                unsigned pk[4];
                #pragma unroll
                for (int c2 = 0; c2 < 2; ++c2) {
                    float4 f4 = *(const float4*)&f2c[q * 8 + c2 * 4];
                    float e0 = f1r + f4.x, e1 = f1r + f4.y;
                    float e2 = f1r + f4.z, e3 = f1r + f4.w;
                    e0 = fmaxf(e0, ALPHA * e0); e1 = fmaxf(e1, ALPHA * e1);
                    e2 = fmaxf(e2, ALPHA * e2); e3 = fmaxf(e3, ALPHA * e3);
                    const int b = q * 8 + c2 * 4;
                    float p0 = ((msk >> (b+0)) & 1u) ? __expf(e0) : 0.f;
                    float p1 = ((msk >> (b+1)) & 1u) ? __expf(e1) : 0.f;
                    float p2 = ((msk >> (b+2)) & 1u) ? __expf(e2) : 0.f;
                    float p3 = ((msk >> (b+3)) & 1u) ? __expf(e3) : 0.f;
                    dsum += (p0 + p1) + (p2 + p3);
                    pk[c2*2+0] = (unsigned)f2bf(p0) | ((unsigned)f2bf(p1) << 16);
                    pk[c2*2+1] = (unsigned)f2bf(p2) | ((unsigned)f2bf(p3) << 16);
                }
                uint4 w = {pk[0], pk[1], pk[2], pk[3]};
                *(uint4*)&psB[pr * 128 + ((psub*64 + q*16) ^ prswz)] = w;
            }
        }
        if (it + 1 < ntile) loadW(nti + 1, wreg0, wreg1);
        __syncthreads();                       // tiles visible
        #pragma unroll
        for (int fg = 0; fg < 2; ++fg) {
            const int arw  = wid * 32 + fg * 16 + (lane & 15);
            const int aswz = (arw & 7) << 4;
            #pragma unroll
            for (int ks = 0; ks < 2; ++ks) {
                bf16x8 af = *(const bf16x8*)&psB[arw * 128 + ((ks*64 + kb2) ^ aswz)];
                #pragma unroll
                for (int cf = 0; cf < 4; ++cf) {
                    int brw = cf * 16 + (lane & 15);
                    bf16x8 bfr = *(const bf16x8*)&wsB[brw * 128 + ((ks*64 + kb2) ^ ((brw & 7) << 4))];
                    acc[fg][cf] = __builtin_amdgcn_mfma_f32_16x16x32_bf16(af, bfr, acc[fg][cf], 0, 0, 0);
                }
            }
        }
    }

    dred[pr][psub] = dsum;
    __syncthreads();

    float* pn = pnum + (((size_t)js * NH + h) * NN + row0) * 64;
    #pragma unroll
    for (int fg = 0; fg < 2; ++fg)
        #pragma unroll
        for (int cf = 0; cf < 4; ++cf) {
            int o = cf * 16 + (lane & 15);
            #pragma unroll
            for (int rg = 0; rg < 4; ++rg) {
                int rl = wid * 32 + fg * 16 + (lane >> 4) * 4 + rg;
                pn[(size_t)rl * 64 + o] = acc[fg][cf][rg];
            }
        }
    if (t < ROWS)
        pden[((size_t)js * NH + h) * NN + row0 + t] = dred[t][0] + dred[t][1];
}

// ---------------------------------------------------------------------------
// K4: reduce over JS slices + normalize.
// ---------------------------------------------------------------------------
__global__ __launch_bounds__(256) void k4_red(const float* __restrict__ pnum,
                                              const float* __restrict__ pden,
                                              float* __restrict__ out, int JS) {
    const int idx = blockIdx.x * 256 + threadIdx.x;   // 0..524287
    const int h   = idx >> 16;
    const int rem = idx & 65535;
    const int n   = rem >> 4;
    const int o4  = (rem & 15) * 4;
    float4 s = {0.f, 0.f, 0.f, 0.f};
    float  d = 0.f;
    for (int js = 0; js < JS; ++js) {
        const float* p = pnum + (((size_t)js * NH + h) * NN + n) * 64 + o4;
        float4 v = *(const float4*)p;
        s.x += v.x; s.y += v.y; s.z += v.z; s.w += v.w;
        d += pden[((size_t)js * NH + h) * NN + n];
    }
    float inv = 1.0f / d;
    float4 r = {s.x * inv, s.y * inv, s.z * inv, s.w * inv};
    *(float4*)&out[(size_t)n * (NH * FOUT) + h * FOUT + o4] = r;
}

extern "C" void kernel_launch(void* const* d_in, const int* in_sizes, int n_in,
                              void* d_out, int out_size, void* d_ws, size_t ws_size,
                              hipStream_t stream) {
    const float* x   = (const float*)d_in[0];
    const int*   adj = (const int*)d_in[1];
    const float* W   = (const float*)d_in[2];
    const float* a   = (const float*)d_in[3];
    float* outp = (float*)d_out;

    // workspace layout
    unsigned short* WhTs = (unsigned short*)d_ws;                   // 4 MB (tiled)
    float* f1 = (float*)(WhTs + (size_t)NH * 64 * NN);              // 128 KB
    float* f2 = f1 + NH * NN;                                       // 128 KB
    unsigned long long* bits = (unsigned long long*)(f2 + NH * NN); // 2 MB
    float* pnum = (float*)(bits + (size_t)NN * 64);
    const size_t baseBytes  = (size_t)(pnum - (float*)d_ws) * 4;
    const size_t sliceBytes = (size_t)NH * NN * 65 * 4;             // num+den per slice
    int JS = 1;
    if (ws_size >= baseBytes + 4 * sliceBytes) JS = 4;
    else if (ws_size >= baseBytes + 2 * sliceBytes) JS = 2;
    float* pden = pnum + (size_t)JS * NH * NN * 64;

    kb     <<<dim3(2048),            256, 0, stream>>>(adj, bits);
    kg     <<<dim3(512),             256, 0, stream>>>(x, W, a, WhTs, f1, f2);
    k3_attn<<<dim3(NN/ROWS, NH, JS), 256, 0, stream>>>(bits, WhTs, f1, f2, pnum, pden);
    k4_red <<<dim3(NN*NH*FOUT/4/256), 256, 0, stream>>>(pnum, pden, outp, JS);
}

// Round 9
// 115.851 us; speedup vs baseline: 1.6368x; 1.0030x over previous
//
#include <hip/hip_runtime.h>
#include <hip/hip_bf16.h>

#define NN   4096
#define FIN  512
#define FOUT 64
#define NH   8
#define ALPHA 0.2f
#define ROWS 128
#define LOG2E 1.4426950408889634f

typedef __attribute__((ext_vector_type(8))) short bf16x8;
typedef __attribute__((ext_vector_type(4))) float f32x4;

__device__ __forceinline__ unsigned short f2bf(float x) {
    unsigned u = __float_as_uint(x);
    return (unsigned short)((u + 0x7fffu + ((u >> 16) & 1u)) >> 16);  // RNE
}

__device__ __forceinline__ unsigned pk2(float a, float b) {
    union { __hip_bfloat162 h2; unsigned u; } cv;
    cv.h2 = __float22bfloat162_rn(float2{a, b});   // low 16 = a (RNE)
    return cv.u;
}

// ---------------------------------------------------------------------------
// KBG (merged for overlap):
//   blocks [0, BITB):   adj -> 64-bit masks (ballot, 8-deep unrolled loads)
//   blocks [BITB,+512): Wh GEMM + f1/f2 (prescaled by log2e) + WhTs epilogue
// WhTs layout: [h][tile][8192 B]; 16B chunk (o, kbyte) at byte
//   o*128 + (kbyte ^ ((o&7)<<4))  — k3's LDS swizzle order.
// ---------------------------------------------------------------------------
#define BITB 2048

__global__ __launch_bounds__(256) void kbg(const float* __restrict__ x,
                                           const int*   __restrict__ adj,
                                           const float* __restrict__ W,
                                           const float* __restrict__ aw,
                                           unsigned long long* __restrict__ bits,
                                           unsigned short* __restrict__ WhTs,
                                           float* __restrict__ f1,
                                           float* __restrict__ f2) {
    __shared__ float As[16][68];
    __shared__ float Bs[16][68];
    __shared__ unsigned short Tb[64][80];
    __shared__ float r1[64][16];
    __shared__ float r2[64][16];
    const int t = threadIdx.x;

    if (blockIdx.x < BITB) {
        const int wv   = blockIdx.x * 4 + (t >> 6);
        const int lane = t & 63;
        const int base = wv * 32;
        #pragma unroll
        for (int r = 0; r < 4; ++r) {
            int v0 = adj[(size_t)(base + r*8 + 0) * 64 + lane];
            int v1 = adj[(size_t)(base + r*8 + 1) * 64 + lane];
            int v2 = adj[(size_t)(base + r*8 + 2) * 64 + lane];
            int v3 = adj[(size_t)(base + r*8 + 3) * 64 + lane];
            int v4 = adj[(size_t)(base + r*8 + 4) * 64 + lane];
            int v5 = adj[(size_t)(base + r*8 + 5) * 64 + lane];
            int v6 = adj[(size_t)(base + r*8 + 6) * 64 + lane];
            int v7 = adj[(size_t)(base + r*8 + 7) * 64 + lane];
            unsigned long long m0 = __ballot(v0 > 0);
            unsigned long long m1 = __ballot(v1 > 0);
            unsigned long long m2 = __ballot(v2 > 0);
            unsigned long long m3 = __ballot(v3 > 0);
            unsigned long long m4 = __ballot(v4 > 0);
            unsigned long long m5 = __ballot(v5 > 0);
            unsigned long long m6 = __ballot(v6 > 0);
            unsigned long long m7 = __ballot(v7 > 0);
            if (lane == 0) {
                ulonglong2* dst = (ulonglong2*)&bits[base + r*8];
                dst[0] = {m0, m1};
                dst[1] = {m2, m3};
                dst[2] = {m4, m5};
                dst[3] = {m6, m7};
            }
        }
        return;
    }

    const int bx   = blockIdx.x - BITB;      // 0..511
    const int h    = bx >> 6;
    const int nti  = bx & 63;
    const int row0 = nti * 64;
    const int tr = t >> 4, tc = t & 15;
    const int ar = t >> 2, ak = t & 3;
    const int bk = t >> 4, bo = t & 15;
    const float* WH = W + (size_t)h * FIN * FOUT;
    float acc[4][4] = {};

    for (int k0i = 0; k0i < FIN; k0i += 16) {
        __syncthreads();
        float4 av = *(const float4*)&x[(size_t)(row0 + ar) * FIN + k0i + ak * 4];
        As[ak*4+0][ar] = av.x; As[ak*4+1][ar] = av.y;
        As[ak*4+2][ar] = av.z; As[ak*4+3][ar] = av.w;
        *(float4*)&Bs[bk][bo*4] =
            *(const float4*)&WH[(size_t)(k0i + bk) * FOUT + bo*4];
        __syncthreads();
        #pragma unroll
        for (int kk = 0; kk < 16; ++kk) {
            float4 a4 = *(const float4*)&As[kk][tr*4];
            float4 b4 = *(const float4*)&Bs[kk][tc*4];
            float a[4] = {a4.x, a4.y, a4.z, a4.w};
            float b[4] = {b4.x, b4.y, b4.z, b4.w};
            #pragma unroll
            for (int i = 0; i < 4; ++i)
                #pragma unroll
                for (int j = 0; j < 4; ++j)
                    acc[i][j] = fmaf(a[i], b[j], acc[i][j]);
        }
    }

    float a1v[4], a2v[4];
    #pragma unroll
    for (int j = 0; j < 4; ++j) {
        a1v[j] = aw[h * 2 * FOUT + tc*4 + j];
        a2v[j] = aw[h * 2 * FOUT + FOUT + tc*4 + j];
    }
    #pragma unroll
    for (int i = 0; i < 4; ++i) {
        float s1 = 0.f, s2 = 0.f;
        #pragma unroll
        for (int j = 0; j < 4; ++j) {
            s1 = fmaf(acc[i][j], a1v[j], s1);
            s2 = fmaf(acc[i][j], a2v[j], s2);
            Tb[tc*4 + j][tr*4 + i] = f2bf(acc[i][j]);
        }
        r1[tr*4 + i][tc] = s1;
        r2[tr*4 + i][tc] = s2;
    }
    __syncthreads();
    if (t < 64) {
        float s1 = 0.f, s2 = 0.f;
        #pragma unroll
        for (int k = 0; k < 16; ++k) { s1 += r1[t][k]; s2 += r2[t][k]; }
        f1[h * NN + row0 + t] = s1 * LOG2E;   // prescale: exp(x)=exp2(x*log2e)
        f2[h * NN + row0 + t] = s2 * LOG2E;   // (lrelu commutes with pos scale)
    }
    unsigned char* tileB = (unsigned char*)(WhTs + ((size_t)(h * 64) + nti) * 4096);
    #pragma unroll
    for (int i = 0; i < 2; ++i) {
        int c = t + i * 256;
        int o = c >> 3, nch = c & 7;
        *(uint4*)(tileB + o * 128 + ((nch * 16) ^ ((o & 7) << 4))) =
            *(const uint4*)&Tb[o][nch * 8];
    }
}

// ---------------------------------------------------------------------------
// K3: fused masked softmax + PV (bf16 MFMA), j-split. Proven 2-barrier
// template: sync -> stage(ds_write)+computeP -> sync -> MFMA. ROWS=128.
// Denominator via MFMA with constant ones-B fragment (row-sum of P).
// ---------------------------------------------------------------------------
__global__ __launch_bounds__(256, 4) void k3_attn(
        const unsigned long long* __restrict__ bits,
        const unsigned short* __restrict__ WhTs,
        const float* __restrict__ f1, const float* __restrict__ f2,
        float* __restrict__ pnum, float* __restrict__ pden) {
    __shared__ unsigned char psB[ROWS * 128];   // 16 KB
    __shared__ unsigned char wsB[8192];         //  8 KB
    const int t    = threadIdx.x;
    const int lane = t & 63, wid = t >> 6;
    const int h    = blockIdx.y;
    const int row0 = blockIdx.x * ROWS;
    const int js   = blockIdx.z, JS = gridDim.z;
    const int ntile = (NN / 64) / JS;
    const int nt0   = js * ntile;
    const int pr   = t >> 1, psub = t & 1;     // row 0..127, j-half 0..1
    const float f1r = f1[h * NN + row0 + pr];
    const float* f2h = f2 + h * NN;
    const unsigned long long* bitsRow = bits + (size_t)(row0 + pr) * 64;
    const unsigned short* WTS = WhTs + (size_t)h * 64 * 4096;
    const int prswz = (pr & 7) << 4;
    f32x4 acc[2][4] = {};
    f32x4 accd[2] = {};
    const bf16x8 ones = {0x3F80, 0x3F80, 0x3F80, 0x3F80,
                         0x3F80, 0x3F80, 0x3F80, 0x3F80};   // bf16 1.0 x8

    uint4 wreg0, wreg1;
    auto loadW = [&](int nti, uint4& w0, uint4& w1) {
        const uint4* gt = (const uint4*)(WTS + (size_t)nti * 4096);
        w0 = gt[t];
        w1 = gt[t + 256];
    };
    loadW(nt0, wreg0, wreg1);

    const int kb2 = (lane >> 4) * 16;
    for (int it = 0; it < ntile; ++it) {
        const int nti = nt0 + it;
        __syncthreads();                       // prev MFMA done reading tiles
        *(uint4*)&wsB[t * 16]        = wreg0;
        *(uint4*)&wsB[t * 16 + 4096] = wreg1;
        {
            unsigned msk = (unsigned)(bitsRow[nti] >> (psub << 5));
            const float* f2c = f2h + nti * 64 + psub * 32;
            #pragma unroll
            for (int q = 0; q < 4; ++q) {
                unsigned pk[4];
                #pragma unroll
                for (int c2 = 0; c2 < 2; ++c2) {
                    float4 f4 = *(const float4*)&f2c[q * 8 + c2 * 4];
                    float e0 = f1r + f4.x, e1 = f1r + f4.y;
                    float e2 = f1r + f4.z, e3 = f1r + f4.w;
                    e0 = fmaxf(e0, ALPHA * e0); e1 = fmaxf(e1, ALPHA * e1);
                    e2 = fmaxf(e2, ALPHA * e2); e3 = fmaxf(e3, ALPHA * e3);
                    const int b = q * 8 + c2 * 4;
                    float p0 = ((msk >> (b+0)) & 1u) ? __builtin_amdgcn_exp2f(e0) : 0.f;
                    float p1 = ((msk >> (b+1)) & 1u) ? __builtin_amdgcn_exp2f(e1) : 0.f;
                    float p2 = ((msk >> (b+2)) & 1u) ? __builtin_amdgcn_exp2f(e2) : 0.f;
                    float p3 = ((msk >> (b+3)) & 1u) ? __builtin_amdgcn_exp2f(e3) : 0.f;
                    pk[c2*2+0] = pk2(p0, p1);
                    pk[c2*2+1] = pk2(p2, p3);
                }
                uint4 w = {pk[0], pk[1], pk[2], pk[3]};
                *(uint4*)&psB[pr * 128 + ((psub*64 + q*16) ^ prswz)] = w;
            }
        }
        if (it + 1 < ntile) loadW(nti + 1, wreg0, wreg1);
        __syncthreads();                       // tiles visible
        #pragma unroll
        for (int fg = 0; fg < 2; ++fg) {
            const int arw  = wid * 32 + fg * 16 + (lane & 15);
            const int aswz = (arw & 7) << 4;
            #pragma unroll
            for (int ks = 0; ks < 2; ++ks) {
                bf16x8 af = *(const bf16x8*)&psB[arw * 128 + ((ks*64 + kb2) ^ aswz)];
                accd[fg] = __builtin_amdgcn_mfma_f32_16x16x32_bf16(af, ones, accd[fg], 0, 0, 0);
                #pragma unroll
                for (int cf = 0; cf < 4; ++cf) {
                    int brw = cf * 16 + (lane & 15);
                    bf16x8 bfr = *(const bf16x8*)&wsB[brw * 128 + ((ks*64 + kb2) ^ ((brw & 7) << 4))];
                    acc[fg][cf] = __builtin_amdgcn_mfma_f32_16x16x32_bf16(af, bfr, acc[fg][cf], 0, 0, 0);
                }
            }
        }
    }

    float* pn = pnum + (((size_t)js * NH + h) * NN + row0) * 64;
    #pragma unroll
    for (int fg = 0; fg < 2; ++fg)
        #pragma unroll
        for (int cf = 0; cf < 4; ++cf) {
            int o = cf * 16 + (lane & 15);
            #pragma unroll
            for (int rg = 0; rg < 4; ++rg) {
                int rl = wid * 32 + fg * 16 + (lane >> 4) * 4 + rg;
                pn[(size_t)rl * 64 + o] = acc[fg][cf][rg];
            }
        }
    if ((lane & 15) == 0) {                    // col-0 lanes hold den[row]
        float* pd = pden + ((size_t)js * NH + h) * NN + row0;
        #pragma unroll
        for (int fg = 0; fg < 2; ++fg)
            #pragma unroll
            for (int rg = 0; rg < 4; ++rg)
                pd[wid * 32 + fg * 16 + (lane >> 4) * 4 + rg] = accd[fg][rg];
    }
}

// ---------------------------------------------------------------------------
// K4: reduce over JS slices + normalize.
// ---------------------------------------------------------------------------
__global__ __launch_bounds__(256) void k4_red(const float* __restrict__ pnum,
                                              const float* __restrict__ pden,
                                              float* __restrict__ out, int JS) {
    const int idx = blockIdx.x * 256 + threadIdx.x;   // 0..524287
    const int h   = idx >> 16;
    const int rem = idx & 65535;
    const int n   = rem >> 4;
    const int o4  = (rem & 15) * 4;
    float4 s = {0.f, 0.f, 0.f, 0.f};
    float  d = 0.f;
    for (int js = 0; js < JS; ++js) {
        const float* p = pnum + (((size_t)js * NH + h) * NN + n) * 64 + o4;
        float4 v = *(const float4*)p;
        s.x += v.x; s.y += v.y; s.z += v.z; s.w += v.w;
        d += pden[((size_t)js * NH + h) * NN + n];
    }
    float inv = 1.0f / d;
    float4 r = {s.x * inv, s.y * inv, s.z * inv, s.w * inv};
    *(float4*)&out[(size_t)n * (NH * FOUT) + h * FOUT + o4] = r;
}

extern "C" void kernel_launch(void* const* d_in, const int* in_sizes, int n_in,
                              void* d_out, int out_size, void* d_ws, size_t ws_size,
                              hipStream_t stream) {
    const float* x   = (const float*)d_in[0];
    const int*   adj = (const int*)d_in[1];
    const float* W   = (const float*)d_in[2];
    const float* a   = (const float*)d_in[3];
    float* outp = (float*)d_out;

    // workspace layout
    unsigned short* WhTs = (unsigned short*)d_ws;                   // 4 MB (tiled)
    float* f1 = (float*)(WhTs + (size_t)NH * 64 * NN);              // 128 KB
    float* f2 = f1 + NH * NN;                                       // 128 KB
    unsigned long long* bits = (unsigned long long*)(f2 + NH * NN); // 2 MB
    float* pnum = (float*)(bits + (size_t)NN * 64);
    const size_t baseBytes  = (size_t)(pnum - (float*)d_ws) * 4;
    const size_t sliceBytes = (size_t)NH * NN * 65 * 4;             // num+den per slice
    int JS = 1;
    if (ws_size >= baseBytes + 4 * sliceBytes) JS = 4;
    else if (ws_size >= baseBytes + 2 * sliceBytes) JS = 2;
    float* pden = pnum + (size_t)JS * NH * NN * 64;

    kbg    <<<dim3(BITB + 512),      256, 0, stream>>>(x, adj, W, a, bits, WhTs, f1, f2);
    k3_attn<<<dim3(NN/ROWS, NH, JS), 256, 0, stream>>>(bits, WhTs, f1, f2, pnum, pden);
    k4_red <<<dim3(NN*NH*FOUT/4/256), 256, 0, stream>>>(pnum, pden, outp, JS);
}

// Round 10
// 109.629 us; speedup vs baseline: 1.7297x; 1.0568x over previous
//
#include <hip/hip_runtime.h>
#include <hip/hip_bf16.h>

#define NN   4096
#define FIN  512
#define FOUT 64
#define NH   8
#define ALPHA 0.2f
#define ROWS 128
#define LOG2E 1.4426950408889634f

typedef __attribute__((ext_vector_type(8))) short bf16x8;
typedef __attribute__((ext_vector_type(4))) float f32x4;

__device__ __forceinline__ unsigned short f2bf(float x) {
    unsigned u = __float_as_uint(x);
    return (unsigned short)((u + 0x7fffu + ((u >> 16) & 1u)) >> 16);  // RNE
}

__device__ __forceinline__ unsigned pk2(float a, float b) {
    union { __hip_bfloat162 h2; unsigned u; } cv;
    cv.h2 = __float22bfloat162_rn(float2{a, b});   // low 16 = a (RNE)
    return cv.u;
}

// ---------------------------------------------------------------------------
// KB: adj -> 64-bit masks. No LDS (full occupancy), 8 loads in flight per
// wave, ballots stored pairwise by lane 0. (Proven R8 kernel — split from
// the GEMM: fusing them twice cost ~40 µs via LDS-capped occupancy.)
// ---------------------------------------------------------------------------
__global__ __launch_bounds__(256) void kb(const int* __restrict__ adj,
                                          unsigned long long* __restrict__ bits) {
    const int wv   = blockIdx.x * 4 + (threadIdx.x >> 6);
    const int lane = threadIdx.x & 63;
    const int base = wv * 32;
    #pragma unroll
    for (int r = 0; r < 4; ++r) {
        int v0 = adj[(size_t)(base + r*8 + 0) * 64 + lane];
        int v1 = adj[(size_t)(base + r*8 + 1) * 64 + lane];
        int v2 = adj[(size_t)(base + r*8 + 2) * 64 + lane];
        int v3 = adj[(size_t)(base + r*8 + 3) * 64 + lane];
        int v4 = adj[(size_t)(base + r*8 + 4) * 64 + lane];
        int v5 = adj[(size_t)(base + r*8 + 5) * 64 + lane];
        int v6 = adj[(size_t)(base + r*8 + 6) * 64 + lane];
        int v7 = adj[(size_t)(base + r*8 + 7) * 64 + lane];
        unsigned long long m0 = __ballot(v0 > 0);
        unsigned long long m1 = __ballot(v1 > 0);
        unsigned long long m2 = __ballot(v2 > 0);
        unsigned long long m3 = __ballot(v3 > 0);
        unsigned long long m4 = __ballot(v4 > 0);
        unsigned long long m5 = __ballot(v5 > 0);
        unsigned long long m6 = __ballot(v6 > 0);
        unsigned long long m7 = __ballot(v7 > 0);
        if (lane == 0) {
            ulonglong2* dst = (ulonglong2*)&bits[base + r*8];
            dst[0] = {m0, m1};
            dst[1] = {m2, m3};
            dst[2] = {m4, m5};
            dst[3] = {m6, m7};
        }
    }
}

// ---------------------------------------------------------------------------
// KG: Wh GEMM + f1/f2 (prescaled by log2e for k3's exp2) + bf16 WhTs
// (tiled+swizzled) epilogue. Proven R8 kernel + 2-line prescale.
// WhTs layout: [h][tile][8192 B]; 16B chunk (o, kbyte) at byte
//   o*128 + (kbyte ^ ((o&7)<<4))  — k3's LDS swizzle order.
// ---------------------------------------------------------------------------
__global__ __launch_bounds__(256) void kg(const float* __restrict__ x,
                                          const float* __restrict__ W,
                                          const float* __restrict__ aw,
                                          unsigned short* __restrict__ WhTs,
                                          float* __restrict__ f1,
                                          float* __restrict__ f2) {
    __shared__ float As[16][68];
    __shared__ float Bs[16][68];
    __shared__ unsigned short Tb[64][80];
    __shared__ float r1[64][16];
    __shared__ float r2[64][16];
    const int t = threadIdx.x;
    const int bx   = blockIdx.x;             // 0..511
    const int h    = bx >> 6;
    const int nti  = bx & 63;
    const int row0 = nti * 64;
    const int tr = t >> 4, tc = t & 15;
    const int ar = t >> 2, ak = t & 3;
    const int bk = t >> 4, bo = t & 15;
    const float* WH = W + (size_t)h * FIN * FOUT;
    float acc[4][4] = {};

    for (int k0i = 0; k0i < FIN; k0i += 16) {
        __syncthreads();
        float4 av = *(const float4*)&x[(size_t)(row0 + ar) * FIN + k0i + ak * 4];
        As[ak*4+0][ar] = av.x; As[ak*4+1][ar] = av.y;
        As[ak*4+2][ar] = av.z; As[ak*4+3][ar] = av.w;
        *(float4*)&Bs[bk][bo*4] =
            *(const float4*)&WH[(size_t)(k0i + bk) * FOUT + bo*4];
        __syncthreads();
        #pragma unroll
        for (int kk = 0; kk < 16; ++kk) {
            float4 a4 = *(const float4*)&As[kk][tr*4];
            float4 b4 = *(const float4*)&Bs[kk][tc*4];
            float a[4] = {a4.x, a4.y, a4.z, a4.w};
            float b[4] = {b4.x, b4.y, b4.z, b4.w};
            #pragma unroll
            for (int i = 0; i < 4; ++i)
                #pragma unroll
                for (int j = 0; j < 4; ++j)
                    acc[i][j] = fmaf(a[i], b[j], acc[i][j]);
        }
    }

    float a1v[4], a2v[4];
    #pragma unroll
    for (int j = 0; j < 4; ++j) {
        a1v[j] = aw[h * 2 * FOUT + tc*4 + j];
        a2v[j] = aw[h * 2 * FOUT + FOUT + tc*4 + j];
    }
    #pragma unroll
    for (int i = 0; i < 4; ++i) {
        float s1 = 0.f, s2 = 0.f;
        #pragma unroll
        for (int j = 0; j < 4; ++j) {
            s1 = fmaf(acc[i][j], a1v[j], s1);
            s2 = fmaf(acc[i][j], a2v[j], s2);
            Tb[tc*4 + j][tr*4 + i] = f2bf(acc[i][j]);
        }
        r1[tr*4 + i][tc] = s1;
        r2[tr*4 + i][tc] = s2;
    }
    __syncthreads();
    if (t < 64) {
        float s1 = 0.f, s2 = 0.f;
        #pragma unroll
        for (int k = 0; k < 16; ++k) { s1 += r1[t][k]; s2 += r2[t][k]; }
        f1[h * NN + row0 + t] = s1 * LOG2E;   // prescale: exp(x)=exp2(x*log2e)
        f2[h * NN + row0 + t] = s2 * LOG2E;   // (lrelu commutes with pos scale)
    }
    unsigned char* tileB = (unsigned char*)(WhTs + ((size_t)(h * 64) + nti) * 4096);
    #pragma unroll
    for (int i = 0; i < 2; ++i) {
        int c = t + i * 256;
        int o = c >> 3, nch = c & 7;
        *(uint4*)(tileB + o * 128 + ((nch * 16) ^ ((o & 7) << 4))) =
            *(const uint4*)&Tb[o][nch * 8];
    }
}

// ---------------------------------------------------------------------------
// K3: fused masked softmax + PV (bf16 MFMA), j-split. Proven 2-barrier
// template: sync -> stage(ds_write)+computeP -> sync -> MFMA. ROWS=128.
// Denominator via MFMA with constant ones-B fragment (row-sum of P).
// (R9 kernel, unchanged — 69.6 -> ~29 µs after exp2/cvt_pk/MFMA-den.)
// ---------------------------------------------------------------------------
__global__ __launch_bounds__(256, 4) void k3_attn(
        const unsigned long long* __restrict__ bits,
        const unsigned short* __restrict__ WhTs,
        const float* __restrict__ f1, const float* __restrict__ f2,
        float* __restrict__ pnum, float* __restrict__ pden) {
    __shared__ unsigned char psB[ROWS * 128];   // 16 KB
    __shared__ unsigned char wsB[8192];         //  8 KB
    const int t    = threadIdx.x;
    const int lane = t & 63, wid = t >> 6;
    const int h    = blockIdx.y;
    const int row0 = blockIdx.x * ROWS;
    const int js   = blockIdx.z, JS = gridDim.z;
    const int ntile = (NN / 64) / JS;
    const int nt0   = js * ntile;
    const int pr   = t >> 1, psub = t & 1;     // row 0..127, j-half 0..1
    const float f1r = f1[h * NN + row0 + pr];
    const float* f2h = f2 + h * NN;
    const unsigned long long* bitsRow = bits + (size_t)(row0 + pr) * 64;
    const unsigned short* WTS = WhTs + (size_t)h * 64 * 4096;
    const int prswz = (pr & 7) << 4;
    f32x4 acc[2][4] = {};
    f32x4 accd[2] = {};
    const bf16x8 ones = {0x3F80, 0x3F80, 0x3F80, 0x3F80,
                         0x3F80, 0x3F80, 0x3F80, 0x3F80};   // bf16 1.0 x8

    uint4 wreg0, wreg1;
    auto loadW = [&](int nti, uint4& w0, uint4& w1) {
        const uint4* gt = (const uint4*)(WTS + (size_t)nti * 4096);
        w0 = gt[t];
        w1 = gt[t + 256];
    };
    loadW(nt0, wreg0, wreg1);

    const int kb2 = (lane >> 4) * 16;
    for (int it = 0; it < ntile; ++it) {
        const int nti = nt0 + it;
        __syncthreads();                       // prev MFMA done reading tiles
        *(uint4*)&wsB[t * 16]        = wreg0;
        *(uint4*)&wsB[t * 16 + 4096] = wreg1;
        {
            unsigned msk = (unsigned)(bitsRow[nti] >> (psub << 5));
            const float* f2c = f2h + nti * 64 + psub * 32;
            #pragma unroll
            for (int q = 0; q < 4; ++q) {
                unsigned pk[4];
                #pragma unroll
                for (int c2 = 0; c2 < 2; ++c2) {
                    float4 f4 = *(const float4*)&f2c[q * 8 + c2 * 4];
                    float e0 = f1r + f4.x, e1 = f1r + f4.y;
                    float e2 = f1r + f4.z, e3 = f1r + f4.w;
                    e0 = fmaxf(e0, ALPHA * e0); e1 = fmaxf(e1, ALPHA * e1);
                    e2 = fmaxf(e2, ALPHA * e2); e3 = fmaxf(e3, ALPHA * e3);
                    const int b = q * 8 + c2 * 4;
                    float p0 = ((msk >> (b+0)) & 1u) ? __builtin_amdgcn_exp2f(e0) : 0.f;
                    float p1 = ((msk >> (b+1)) & 1u) ? __builtin_amdgcn_exp2f(e1) : 0.f;
                    float p2 = ((msk >> (b+2)) & 1u) ? __builtin_amdgcn_exp2f(e2) : 0.f;
                    float p3 = ((msk >> (b+3)) & 1u) ? __builtin_amdgcn_exp2f(e3) : 0.f;
                    pk[c2*2+0] = pk2(p0, p1);
                    pk[c2*2+1] = pk2(p2, p3);
                }
                uint4 w = {pk[0], pk[1], pk[2], pk[3]};
                *(uint4*)&psB[pr * 128 + ((psub*64 + q*16) ^ prswz)] = w;
            }
        }
        if (it + 1 < ntile) loadW(nti + 1, wreg0, wreg1);
        __syncthreads();                       // tiles visible
        #pragma unroll
        for (int fg = 0; fg < 2; ++fg) {
            const int arw  = wid * 32 + fg * 16 + (lane & 15);
            const int aswz = (arw & 7) << 4;
            #pragma unroll
            for (int ks = 0; ks < 2; ++ks) {
                bf16x8 af = *(const bf16x8*)&psB[arw * 128 + ((ks*64 + kb2) ^ aswz)];
                accd[fg] = __builtin_amdgcn_mfma_f32_16x16x32_bf16(af, ones, accd[fg], 0, 0, 0);
                #pragma unroll
                for (int cf = 0; cf < 4; ++cf) {
                    int brw = cf * 16 + (lane & 15);
                    bf16x8 bfr = *(const bf16x8*)&wsB[brw * 128 + ((ks*64 + kb2) ^ ((brw & 7) << 4))];
                    acc[fg][cf] = __builtin_amdgcn_mfma_f32_16x16x32_bf16(af, bfr, acc[fg][cf], 0, 0, 0);
                }
            }
        }
    }

    float* pn = pnum + (((size_t)js * NH + h) * NN + row0) * 64;
    #pragma unroll
    for (int fg = 0; fg < 2; ++fg)
        #pragma unroll
        for (int cf = 0; cf < 4; ++cf) {
            int o = cf * 16 + (lane & 15);
            #pragma unroll
            for (int rg = 0; rg < 4; ++rg) {
                int rl = wid * 32 + fg * 16 + (lane >> 4) * 4 + rg;
                pn[(size_t)rl * 64 + o] = acc[fg][cf][rg];
            }
        }
    if ((lane & 15) == 0) {                    // col-0 lanes hold den[row]
        float* pd = pden + ((size_t)js * NH + h) * NN + row0;
        #pragma unroll
        for (int fg = 0; fg < 2; ++fg)
            #pragma unroll
            for (int rg = 0; rg < 4; ++rg)
                pd[wid * 32 + fg * 16 + (lane >> 4) * 4 + rg] = accd[fg][rg];
    }
}

// ---------------------------------------------------------------------------
// K4: reduce over JS slices + normalize.
// ---------------------------------------------------------------------------
__global__ __launch_bounds__(256) void k4_red(const float* __restrict__ pnum,
                                              const float* __restrict__ pden,
                                              float* __restrict__ out, int JS) {
    const int idx = blockIdx.x * 256 + threadIdx.x;   // 0..524287
    const int h   = idx >> 16;
    const int rem = idx & 65535;
    const int n   = rem >> 4;
    const int o4  = (rem & 15) * 4;
    float4 s = {0.f, 0.f, 0.f, 0.f};
    float  d = 0.f;
    for (int js = 0; js < JS; ++js) {
        const float* p = pnum + (((size_t)js * NH + h) * NN + n) * 64 + o4;
        float4 v = *(const float4*)p;
        s.x += v.x; s.y += v.y; s.z += v.z; s.w += v.w;
        d += pden[((size_t)js * NH + h) * NN + n];
    }
    float inv = 1.0f / d;
    float4 r = {s.x * inv, s.y * inv, s.z * inv, s.w * inv};
    *(float4*)&out[(size_t)n * (NH * FOUT) + h * FOUT + o4] = r;
}

extern "C" void kernel_launch(void* const* d_in, const int* in_sizes, int n_in,
                              void* d_out, int out_size, void* d_ws, size_t ws_size,
                              hipStream_t stream) {
    const float* x   = (const float*)d_in[0];
    const int*   adj = (const int*)d_in[1];
    const float* W   = (const float*)d_in[2];
    const float* a   = (const float*)d_in[3];
    float* outp = (float*)d_out;

    // workspace layout
    unsigned short* WhTs = (unsigned short*)d_ws;                   // 4 MB (tiled)
    float* f1 = (float*)(WhTs + (size_t)NH * 64 * NN);              // 128 KB
    float* f2 = f1 + NH * NN;                                       // 128 KB
    unsigned long long* bits = (unsigned long long*)(f2 + NH * NN); // 2 MB
    float* pnum = (float*)(bits + (size_t)NN * 64);
    const size_t baseBytes  = (size_t)(pnum - (float*)d_ws) * 4;
    const size_t sliceBytes = (size_t)NH * NN * 65 * 4;             // num+den per slice
    int JS = 1;
    if (ws_size >= baseBytes + 4 * sliceBytes) JS = 4;
    else if (ws_size >= baseBytes + 2 * sliceBytes) JS = 2;
    float* pden = pnum + (size_t)JS * NH * NN * 64;

    kb     <<<dim3(2048),            256, 0, stream>>>(adj, bits);
    kg     <<<dim3(512),             256, 0, stream>>>(x, W, a, WhTs, f1, f2);
    k3_attn<<<dim3(NN/ROWS, NH, JS), 256, 0, stream>>>(bits, WhTs, f1, f2, pnum, pden);
    k4_red <<<dim3(NN*NH*FOUT/4/256), 256, 0, stream>>>(pnum, pden, outp, JS);
}